// Round 2
// baseline (49.490 us; speedup 1.0000x reference)
//
#include <hip/hip_runtime.h>

#define K_HP 0.0244f
#define I_THRESH 0.39063f

// tanh(v) = 1 - 2/(1+exp(2v)); NaN-free at both extremes.
__device__ __forceinline__ float tanh_fast(float v) {
    float e = __expf(2.0f * v);                       // v_exp_f32 path
    float r = __builtin_amdgcn_rcpf(1.0f + e);        // v_rcp_f32, ~1 ulp
    return fmaf(-2.0f, r, 1.0f);
}

constexpr int ROWS = 256;            // rows per tile = threads per block
constexpr int TILE_F4 = ROWS * 13 / 4;  // 832 float4 per tile (13312 B, 16B-aligned)

__global__ __launch_bounds__(256) void pid_kernel(
    const float* __restrict__ x,
    const float* __restrict__ last,
    const float* __restrict__ w1, const float* __restrict__ b1,
    const float* __restrict__ w2, const float* __restrict__ b2,
    const float* __restrict__ w3, const float* __restrict__ b3,
    float* __restrict__ out, int n)
{
    __shared__ float4 lds4[TILE_F4];
    float* lds = (float*)lds4;

    // Wave-uniform weight loads -> scalar loads, hoisted out of the loop.
    float W1[8], B1[8], W2[64], B2[8], W3[8];
    #pragma unroll
    for (int j = 0; j < 8; ++j) { W1[j] = w1[j]; B1[j] = b1[j]; B2[j] = b2[j]; W3[j] = w3[j]; }
    #pragma unroll
    for (int j = 0; j < 64; ++j) W2[j] = w2[j];
    const float B3 = b3[0];

    const float a   = 0.3417968f;   // interior PID_KP value
    const float Kic = 0.1503906f;   // PID_KI is constant everywhere

    const int t = threadIdx.x;
    const int nTiles = (n + ROWS - 1) / ROWS;

    for (int tile = blockIdx.x; tile < nTiles; tile += gridDim.x) {
        const size_t base = (size_t)tile * ROWS * 13;   // dword index of tile start
        const int rowsHere = min(ROWS, n - tile * ROWS);

        if (rowsHere == ROWS) {
            // Fully-coalesced float4 staging: 832 chunks, threads 0..255 x3 + 0..63 x1
            const float4* src = (const float4*)(x + base);
            #pragma unroll
            for (int k = 0; k < 3; ++k) lds4[t + k * 256] = src[t + k * 256];
            if (t < TILE_F4 - 768) lds4[t + 768] = src[t + 768];
        } else {
            for (int j = t; j < rowsHere * 13; j += 256) lds[j] = x[base + j];
        }
        __syncthreads();

        if (t < rowsHere) {
            const int i = tile * ROWS + t;
            float hi   = lds[t * 13 + 5];
            float aim  = lds[t * 13 + 7];
            float rate = lds[t * 13 + 11];

            float d_raw = aim - hi;
            float diff  = d_raw * K_HP;

            // MLP 1->8->8->1
            float h1[8];
            #pragma unroll
            for (int j = 0; j < 8; ++j) h1[j] = tanh_fast(fmaf(diff, W1[j], B1[j]));
            float k_out = B3;
            #pragma unroll
            for (int j = 0; j < 8; ++j) {
                float acc = B2[j];
                #pragma unroll
                for (int k = 0; k < 8; ++k) acc = fmaf(h1[k], W2[k * 8 + j], acc);
                k_out = fmaf(tanh_fast(acc), W3[j], k_out);
            }
            float diff_real = d_raw * k_out;

            // Kp interp: symmetric in diff; constant a on [-2.5,2.5], lerp to 0.5 at +-10
            float ad = fabsf(diff);
            float tt = fminf(fmaxf((ad - 2.5f) * (1.0f / 7.5f), 0.0f), 1.0f);
            float Kp = fmaf(tt, 0.5f - a, a) * rate;
            float Ki = Kic * rate;

            float ivalue = (ad < I_THRESH) ? 0.0f : diff_real * 0.5f;
            out[i] = last[i] + fmaf(Ki, ivalue, Kp * diff_real);
        }
        __syncthreads();   // protect LDS before next tile's overwrite
    }
}

extern "C" void kernel_launch(void* const* d_in, const int* in_sizes, int n_in,
                              void* d_out, int out_size, void* d_ws, size_t ws_size,
                              hipStream_t stream) {
    const float* x    = (const float*)d_in[0];
    const float* last = (const float*)d_in[1];
    const float* w1   = (const float*)d_in[2];
    const float* b1   = (const float*)d_in[3];
    const float* w2   = (const float*)d_in[4];
    const float* b2   = (const float*)d_in[5];
    const float* w3   = (const float*)d_in[6];
    const float* b3   = (const float*)d_in[7];
    float* out = (float*)d_out;
    int n = out_size;
    int nTiles = (n + ROWS - 1) / ROWS;
    int grid = nTiles < 4096 ? nTiles : 4096;
    pid_kernel<<<grid, 256, 0, stream>>>(x, last, w1, b1, w2, b2, w3, b3, out, n);
}

// Round 3
// 46.604 us; speedup vs baseline: 1.0619x; 1.0619x over previous
//
#include <hip/hip_runtime.h>

#define K_HP 0.0244f
#define I_THRESH 0.39063f

// tanh(v) = 1 - 2/(1+exp(2v)); NaN-free at both extremes.
__device__ __forceinline__ float tanh_fast(float v) {
    float e = __expf(2.0f * v);                       // v_exp_f32 path
    float r = __builtin_amdgcn_rcpf(1.0f + e);        // v_rcp_f32, ~1 ulp
    return fmaf(-2.0f, r, 1.0f);
}

struct Weights {
    float W1[8], B1[8], W2[64], B2[8], W3[8], B3;
};

__device__ __forceinline__ float row_compute(float hi, float aim, float rate,
                                             float lst, const Weights& w) {
    const float a   = 0.3417968f;   // interior PID_KP value
    const float Kic = 0.1503906f;   // PID_KI is constant everywhere

    float d_raw = aim - hi;
    float diff  = d_raw * K_HP;

    float h1[8];
    #pragma unroll
    for (int j = 0; j < 8; ++j) h1[j] = tanh_fast(fmaf(diff, w.W1[j], w.B1[j]));
    float k_out = w.B3;
    #pragma unroll
    for (int j = 0; j < 8; ++j) {
        float acc = w.B2[j];
        #pragma unroll
        for (int k = 0; k < 8; ++k) acc = fmaf(h1[k], w.W2[k * 8 + j], acc);
        k_out = fmaf(tanh_fast(acc), w.W3[j], k_out);
    }
    float diff_real = d_raw * k_out;

    float ad = fabsf(diff);
    float t  = fminf(fmaxf((ad - 2.5f) * (1.0f / 7.5f), 0.0f), 1.0f);
    float Kp = fmaf(t, 0.5f - a, a) * rate;
    float Ki = Kic * rate;

    float ivalue = (ad < I_THRESH) ? 0.0f : diff_real * 0.5f;
    return lst + fmaf(Ki, ivalue, Kp * diff_real);
}

__global__ __launch_bounds__(256) void pid_kernel(
    const float* __restrict__ x,
    const float* __restrict__ last,
    const float* __restrict__ w1, const float* __restrict__ b1,
    const float* __restrict__ w2, const float* __restrict__ b2,
    const float* __restrict__ w3, const float* __restrict__ b3,
    float* __restrict__ out, int n)
{
    // Wave-uniform weight loads -> scalar loads, hoisted out of the loop.
    Weights w;
    #pragma unroll
    for (int j = 0; j < 8; ++j) { w.W1[j] = w1[j]; w.B1[j] = b1[j]; w.B2[j] = b2[j]; w.W3[j] = w3[j]; }
    #pragma unroll
    for (int j = 0; j < 64; ++j) w.W2[j] = w2[j];
    w.B3 = b3[0];

    const int tid    = blockIdx.x * blockDim.x + threadIdx.x;
    const int stride = gridDim.x * blockDim.x;

    int i = tid;
    // Main loop: 4 rows per iteration -> 16 loads in flight, 4x compute ILP.
    for (; i + 3 * stride < n; i += 4 * stride) {
        int   idx[4];
        float hi[4], aim[4], rate[4], lst[4];
        #pragma unroll
        for (int u = 0; u < 4; ++u) {
            idx[u] = i + u * stride;
            const float* row = x + (size_t)idx[u] * 13;
            hi[u]   = row[5];
            aim[u]  = row[7];
            rate[u] = row[11];
            lst[u]  = last[idx[u]];
        }
        float res[4];
        #pragma unroll
        for (int u = 0; u < 4; ++u)
            res[u] = row_compute(hi[u], aim[u], rate[u], lst[u], w);
        #pragma unroll
        for (int u = 0; u < 4; ++u)
            out[idx[u]] = res[u];
    }
    // Tail (not taken for n = 4194304 with grid 2048x256, kept for generality).
    for (; i < n; i += stride) {
        const float* row = x + (size_t)i * 13;
        out[i] = row_compute(row[5], row[7], row[11], last[i], w);
    }
}

extern "C" void kernel_launch(void* const* d_in, const int* in_sizes, int n_in,
                              void* d_out, int out_size, void* d_ws, size_t ws_size,
                              hipStream_t stream) {
    const float* x    = (const float*)d_in[0];
    const float* last = (const float*)d_in[1];
    const float* w1   = (const float*)d_in[2];
    const float* b1   = (const float*)d_in[3];
    const float* w2   = (const float*)d_in[4];
    const float* b2   = (const float*)d_in[5];
    const float* w3   = (const float*)d_in[6];
    const float* b3   = (const float*)d_in[7];
    float* out = (float*)d_out;
    int n = out_size;
    pid_kernel<<<2048, 256, 0, stream>>>(x, last, w1, b1, w2, b2, w3, b3, out, n);
}